// Round 10
// baseline (212.644 us; speedup 1.0000x reference)
//
#include <hip/hip_runtime.h>
#include <hip/hip_bf16.h>
#include <math.h>

#define M_TOT   16384      // B*N = 4*4096
#define F_DIM   768
#define C_DIM   64
#define P_DIM   8192
#define EPSN    1e-12f
#define NEG_BIG (-3.402823466e38f)
#define NCH     16
#define PCH     (P_DIM / NCH)   // 512
#define GRP     32
#define NGRP    (P_DIM / GRP)   // 256
#define MARG    1e-2f           // >= 2 * 4e-3 hard bf16x1 screen error bound

typedef __attribute__((ext_vector_type(8))) short bf16x8;
typedef __attribute__((ext_vector_type(4))) float f32x4;
typedef unsigned short ushort_t;

__device__ inline ushort_t bf16hi(float v) {
    __hip_bfloat16 hb = __float2bfloat16(v);
    return *reinterpret_cast<ushort_t*>(&hb);
}

// ---------------- Kernel A: cn = l2norm(codebook) + bf16 round ----------------
__global__ void k_norm_cb(const float* __restrict__ cb, float* __restrict__ cn,
                          ushort_t* __restrict__ ch) {
    int wv = threadIdx.x >> 6, lane = threadIdx.x & 63;
    int row = blockIdx.x * 4 + wv;
    float v = cb[(size_t)row * C_DIM + lane];
    float s = v * v;
    #pragma unroll
    for (int o = 32; o; o >>= 1) s += __shfl_xor(s, o, 64);
    float inv = 1.0f / fmaxf(sqrtf(s), EPSN);
    float nv = v * inv;
    size_t i = (size_t)row * C_DIM + lane;
    cn[i] = nv;
    ch[i] = bf16hi(nv);
}

// ---------------- Kernel A2: w_outT[c][f] = w_out[f][c] ----------------
__global__ void k_transpose_wout(const float* __restrict__ w_out, float* __restrict__ wT) {
    int i = blockIdx.x * 256 + threadIdx.x;   // 49152 total
    int f = i >> 6, c = i & 63;
    wT[(size_t)c * F_DIM + f] = w_out[i];
}

// ---------------- Kernel B: zn = l2norm(z @ w_in^T), tiled LDS fp32 GEMM ----------
// T14 async staging: prefetch chunk k+1 (global->reg) issued right after the
// post-ds_write barrier, so HBM latency hides under chunk k's 16-kq compute.
// LDS tiles use 16B-slot XOR swizzle (slot = k4 ^ ((row>>2)&15)): compute reads
// <=2-way (free), staging writes ~4-way on 1/10 of LDS ops. FMA chain per output
// is k-ascending x,y,z,w -- BITWISE identical zn to previous rounds.
#define PBM 32
#define PKC 64
__global__ __launch_bounds__(128)
void k_proj(const float* __restrict__ z, const float* __restrict__ w_in,
            float* __restrict__ zn, ushort_t* __restrict__ zh) {
    __shared__ float lz[PBM * PKC];     // 8 KB   [row][slot*4]
    __shared__ float lw[C_DIM * PKC];   // 16 KB  [c][slot*4]

    const int t  = threadIdx.x;
    const int m0 = blockIdx.x * PBM;
    const int r0 = (t >> 4) * 4;        // rows r0..r0+3
    const int c0 = (t & 15) * 4;        // cols c0..c0+3
    const int zswz = t >> 4;            // == ((r0+ri)>>2)&15 for ri<4
    const int wswz = t & 15;            // == ((c0+cj)>>2)&15 for cj<4

    float acc[4][4];
    #pragma unroll
    for (int i = 0; i < 4; ++i)
        #pragma unroll
        for (int j = 0; j < 4; ++j) acc[i][j] = 0.0f;

    float4 pz[4], pw[8];
    // prefetch chunk 0
    #pragma unroll
    for (int i = 0; i < 4; ++i) {
        int f4 = i * 128 + t; int row = f4 >> 4, k4 = f4 & 15;
        pz[i] = *(const float4*)(z + (size_t)(m0 + row) * F_DIM + k4 * 4);
    }
    #pragma unroll
    for (int i = 0; i < 8; ++i) {
        int f4 = i * 128 + t; int c = f4 >> 4, k4 = f4 & 15;
        pw[i] = *(const float4*)(w_in + (size_t)c * F_DIM + k4 * 4);
    }

    for (int k0 = 0; k0 < F_DIM; k0 += PKC) {       // 12 chunks
        __syncthreads();                // previous compute done; LDS reusable
        #pragma unroll
        for (int i = 0; i < 4; ++i) {
            int f4 = i * 128 + t; int row = f4 >> 4, k4 = f4 & 15;
            *(float4*)(lz + row * PKC + ((k4 ^ ((row >> 2) & 15)) * 4)) = pz[i];
        }
        #pragma unroll
        for (int i = 0; i < 8; ++i) {
            int f4 = i * 128 + t; int c = f4 >> 4, k4 = f4 & 15;
            *(float4*)(lw + c * PKC + ((k4 ^ ((c >> 2) & 15)) * 4)) = pw[i];
        }
        __syncthreads();

        if (k0 + PKC < F_DIM) {         // prefetch next chunk during compute
            #pragma unroll
            for (int i = 0; i < 4; ++i) {
                int f4 = i * 128 + t; int row = f4 >> 4, k4 = f4 & 15;
                pz[i] = *(const float4*)(z + (size_t)(m0 + row) * F_DIM + k0 + PKC + k4 * 4);
            }
            #pragma unroll
            for (int i = 0; i < 8; ++i) {
                int f4 = i * 128 + t; int c = f4 >> 4, k4 = f4 & 15;
                pw[i] = *(const float4*)(w_in + (size_t)c * F_DIM + k0 + PKC + k4 * 4);
            }
        }

        #pragma unroll
        for (int kq = 0; kq < 16; ++kq) {
            float4 zf[4], wf[4];
            int zo = (kq ^ zswz) * 4;
            int wo = (kq ^ wswz) * 4;
            #pragma unroll
            for (int ri = 0; ri < 4; ++ri)
                zf[ri] = *(const float4*)(lz + (r0 + ri) * PKC + zo);
            #pragma unroll
            for (int cj = 0; cj < 4; ++cj)
                wf[cj] = *(const float4*)(lw + (c0 + cj) * PKC + wo);
            #pragma unroll
            for (int ri = 0; ri < 4; ++ri)
                #pragma unroll
                for (int cj = 0; cj < 4; ++cj) {
                    acc[ri][cj] = fmaf(zf[ri].x, wf[cj].x, acc[ri][cj]);
                    acc[ri][cj] = fmaf(zf[ri].y, wf[cj].y, acc[ri][cj]);
                    acc[ri][cj] = fmaf(zf[ri].z, wf[cj].z, acc[ri][cj]);
                    acc[ri][cj] = fmaf(zf[ri].w, wf[cj].w, acc[ri][cj]);
                }
        }
    }

    // ---- epilogue: row-norm (16-lane group holds one row's 64 c) ----
    #pragma unroll
    for (int ri = 0; ri < 4; ++ri) {
        float s = acc[ri][0] * acc[ri][0] + acc[ri][1] * acc[ri][1]
                + acc[ri][2] * acc[ri][2] + acc[ri][3] * acc[ri][3];
        #pragma unroll
        for (int o = 1; o < 16; o <<= 1) s += __shfl_xor(s, o, 64);
        float inv = 1.0f / fmaxf(sqrtf(s), EPSN);
        float4 v;
        v.x = acc[ri][0] * inv; v.y = acc[ri][1] * inv;
        v.z = acc[ri][2] * inv; v.w = acc[ri][3] * inv;
        size_t base = (size_t)(m0 + r0 + ri) * C_DIM + c0;
        *(float4*)(zn + base) = v;
        ushort4 hv = {bf16hi(v.x), bf16hi(v.y), bf16hi(v.z), bf16hi(v.w)};
        *(ushort4*)(zh + base) = hv;
    }
}

// ---------------- Kernel C: bf16x1 MFMA screen -> per-32-code group maxima ----------
// Single-precision screen: sim_bf16 = zh . ch, |err| <= 4e-3 hard (C-S bound on
// unit rows); k_pick rescans in exact fp32 with MARG = 1e-2 >= 2*err. 2 MFMAs per
// 16(p)x16(m)xK64 tile. gmax[NGRP][M_TOT] hosted in d_out 'out' region.
__global__ __launch_bounds__(256, 4)
void k_simmax(const ushort_t* __restrict__ zh, const ushort_t* __restrict__ ch,
              float* __restrict__ gmax) {
    int wv = threadIdx.x >> 6, l = threadIdx.x & 63;
    int m0 = (blockIdx.x * 4 + wv) * 64;
    int p0 = blockIdx.y * PCH;
    int col = l & 15, quad = l >> 4;
    int kb = quad * 8;

    bf16x8 bh[4][2];
    #pragma unroll
    for (int mt = 0; mt < 4; ++mt) {
        const ushort_t* zr = zh + (size_t)(m0 + mt * 16 + col) * C_DIM + kb;
        #pragma unroll
        for (int ks = 0; ks < 2; ++ks)
            bh[mt][ks] = *(const bf16x8*)(zr + ks * 32);
    }

    for (int g = 0; g < PCH / GRP; ++g) {           // 16 groups of 32 p
        float gm[4];
        #pragma unroll
        for (int mt = 0; mt < 4; ++mt) gm[mt] = NEG_BIG;

        #pragma unroll
        for (int half = 0; half < 2; ++half) {      // 2 16-p tiles per group
            int pt = g * 2 + half;
            size_t prow = (size_t)(p0 + pt * 16 + col) * C_DIM + kb;
            bf16x8 ah0 = *(const bf16x8*)(ch + prow);
            bf16x8 ah1 = *(const bf16x8*)(ch + prow + 32);
            #pragma unroll
            for (int mt = 0; mt < 4; ++mt) {
                f32x4 acc = {0.f, 0.f, 0.f, 0.f};
                acc = __builtin_amdgcn_mfma_f32_16x16x32_bf16(ah0, bh[mt][0], acc, 0, 0, 0);
                acc = __builtin_amdgcn_mfma_f32_16x16x32_bf16(ah1, bh[mt][1], acc, 0, 0, 0);
                float tm = fmaxf(fmaxf(acc[0], acc[1]), fmaxf(acc[2], acc[3]));
                gm[mt] = fmaxf(gm[mt], tm);
            }
        }
        #pragma unroll
        for (int mt = 0; mt < 4; ++mt) {
            float v = gm[mt];
            v = fmaxf(v, __shfl_xor(v, 16, 64));
            v = fmaxf(v, __shfl_xor(v, 32, 64));
            if (quad == 0)
                gmax[(size_t)(blockIdx.y * (PCH / GRP) + g) * M_TOT + m0 + mt * 16 + col] = v;
        }
    }
}

// ---------------- Kernel C2: per-row pick, one WAVE per row, wave-parallel rescan ----
// Lane l holds groups {l, l+64, l+128, l+192}. Row max via shuffle; __ballot flags
// candidate groups; for each flagged group (wave-uniform bit loop, ~1.6/row) all 64
// lanes rescan: lane l does half the dot of code g*32+(l&31) (halves via shfl 32).
// Exact fp32, np tie rules (groups ascending, min p on ties). No LDS, no atomics.
__global__ __launch_bounds__(256)
void k_pick(const float* __restrict__ gmax, const float* __restrict__ zn,
            const float* __restrict__ cn, int* __restrict__ idx_i,
            float* __restrict__ idx_f) {
    int wv = threadIdx.x >> 6, l = threadIdx.x & 63;
    int m = blockIdx.x * 4 + wv;            // one wave per row

    float gv[4];
    #pragma unroll
    for (int b = 0; b < 4; ++b)
        gv[b] = gmax[(size_t)(b * 64 + l) * M_TOT + m];
    float rm = fmaxf(fmaxf(gv[0], gv[1]), fmaxf(gv[2], gv[3]));
    #pragma unroll
    for (int o = 32; o; o >>= 1) rm = fmaxf(rm, __shfl_xor(rm, o, 64));
    float thr = rm - MARG;

    // zn row: lane holds half the row (half = l>>5)
    float zr[32];
    {
        const float4* zp = (const float4*)(zn + (size_t)m * C_DIM + (l >> 5) * 32);
        #pragma unroll
        for (int q = 0; q < 8; ++q) {
            float4 v = zp[q];
            zr[4 * q] = v.x; zr[4 * q + 1] = v.y;
            zr[4 * q + 2] = v.z; zr[4 * q + 3] = v.w;
        }
    }

    float bv = NEG_BIG; int bp = P_DIM;
    #pragma unroll
    for (int b = 0; b < 4; ++b) {           // ascending batches -> ascending groups
        unsigned long long mask = __ballot(gv[b] >= thr);
        while (mask) {
            int j = __ffsll((unsigned long long)mask) - 1;
            mask &= mask - 1;               // ascending j within batch
            int g = b * 64 + j;
            int p = g * GRP + (l & 31);
            const float4* cp = (const float4*)(cn + (size_t)p * C_DIM + (l >> 5) * 32);
            float a0 = 0.f, a1 = 0.f, a2 = 0.f, a3 = 0.f;
            #pragma unroll
            for (int q = 0; q < 8; ++q) {
                float4 w = cp[q];
                a0 = fmaf(w.x, zr[4 * q + 0], a0);
                a1 = fmaf(w.y, zr[4 * q + 1], a1);
                a2 = fmaf(w.z, zr[4 * q + 2], a2);
                a3 = fmaf(w.w, zr[4 * q + 3], a3);
            }
            float s = (a0 + a1) + (a2 + a3);
            s += __shfl_xor(s, 32, 64);     // combine halves: full dot in both lanes
            if (s > bv || (s == bv && p < bp)) { bv = s; bp = p; }
        }
    }
    #pragma unroll
    for (int o = 32; o; o >>= 1) {
        float ov = __shfl_xor(bv, o, 64);
        int   op = __shfl_xor(bp, o, 64);
        if (ov > bv || (ov == bv && op < bp)) { bv = ov; bp = op; }
    }
    if (l == 0) { idx_i[m] = bp; idx_f[m] = (float)bp; }
}

// ---------------- Kernel D: out = codes @ w_outT ----------------
#define D_ROWS 128
__global__ void k_out(const int* __restrict__ idx, const float* __restrict__ cn,
                      const float* __restrict__ wT, float* __restrict__ out) {
    int wv = threadIdx.x >> 6, lane = threadIdx.x & 63;
    int f  = blockIdx.y * 64 + lane;
    int m0 = blockIdx.x * D_ROWS + wv * 32;

    float wcol[64];
    #pragma unroll
    for (int c = 0; c < 64; ++c) wcol[c] = wT[(size_t)c * F_DIM + f];

    #pragma unroll 4
    for (int r = 0; r < 32; ++r) {
        int m = __builtin_amdgcn_readfirstlane(m0 + r);
        const float4* cp = (const float4*)(cn + (size_t)idx[m] * C_DIM);
        float acc = 0.f;
        #pragma unroll
        for (int j = 0; j < 16; ++j) {
            float4 cv = cp[j];
            acc = fmaf(cv.x, wcol[4 * j + 0], acc);
            acc = fmaf(cv.y, wcol[4 * j + 1], acc);
            acc = fmaf(cv.z, wcol[4 * j + 2], acc);
            acc = fmaf(cv.w, wcol[4 * j + 3], acc);
        }
        out[(size_t)m * F_DIM + f] = acc;
    }
}

// ---------------- Kernel E: per-block loss partials ----------------
__global__ void k_loss(const float* __restrict__ zn, const float* __restrict__ cn,
                       const int* __restrict__ idx, float* __restrict__ lossp) {
    __shared__ float wsum[4];
    int wv = threadIdx.x >> 6, lane = threadIdx.x & 63;
    int m = blockIdx.x * 4 + wv;
    int ci = idx[m];
    float zv = zn[(size_t)m * C_DIM + lane];
    float cv = cn[(size_t)ci * C_DIM + lane];
    float d = zv - cv;
    float s = d * d;
    #pragma unroll
    for (int o = 32; o; o >>= 1) s += __shfl_xor(s, o, 64);
    if (lane == 0) wsum[wv] = s;
    __syncthreads();
    if (threadIdx.x == 0) lossp[blockIdx.x] = (wsum[0] + wsum[1]) + (wsum[2] + wsum[3]);
}

__global__ void k_loss_final(const float* __restrict__ lossp, float* __restrict__ loss_out) {
    __shared__ float sh[256];
    float s = 0.f;
    for (int i = threadIdx.x; i < 4096; i += 256) s += lossp[i];
    sh[threadIdx.x] = s;
    __syncthreads();
    for (int o = 128; o; o >>= 1) {
        if (threadIdx.x < o) sh[threadIdx.x] += sh[threadIdx.x + o];
        __syncthreads();
    }
    if (threadIdx.x == 0)
        loss_out[0] = 1.25f * sh[0] / (float)(M_TOT * C_DIM);
}

extern "C" void kernel_launch(void* const* d_in, const int* in_sizes, int n_in,
                              void* d_out, int out_size, void* d_ws, size_t ws_size,
                              hipStream_t stream) {
    const float* z     = (const float*)d_in[0];
    const float* w_in  = (const float*)d_in[1];
    const float* w_out = (const float*)d_in[2];
    const float* cb    = (const float*)d_in[3];

    float* out    = (float*)d_out;
    float* lossO  = out + (size_t)M_TOT * F_DIM;
    float* idxO   = lossO + 1;
    // gmax (16.8 MB) lives in the d_out 'out' region: written by k_simmax, read
    // by k_pick, then fully overwritten by k_out afterwards (stream-ordered).
    float* gmax   = out;

    float* ws    = (float*)d_ws;                          // total ~9.4 MB
    float* cn    = ws;                                    // 524288 f   (2 MB)
    float* zn    = cn + (size_t)P_DIM * C_DIM;            // 1048576 f  (4 MB)
    float* wT    = zn + (size_t)M_TOT * C_DIM;            // 49152 f
    float* lossp = wT + (size_t)C_DIM * F_DIM;            // 4096 f
    int*   idxi  = (int*)(lossp + 4096);                  // 16384 i
    ushort_t* zh = (ushort_t*)(idxi + M_TOT);             // 1048576 us (2 MB)
    ushort_t* ch = zh + (size_t)M_TOT * C_DIM;            // 524288 us  (1 MB)

    k_norm_cb<<<P_DIM / 4, 256, 0, stream>>>(cb, cn, ch);
    k_transpose_wout<<<(C_DIM * F_DIM) / 256, 256, 0, stream>>>(w_out, wT);
    k_proj<<<M_TOT / PBM, 128, 0, stream>>>(z, w_in, zn, zh);

    dim3 gC(M_TOT / 256, NCH);
    k_simmax<<<gC, 256, 0, stream>>>(zh, ch, gmax);
    k_pick<<<M_TOT / 4, 256, 0, stream>>>(gmax, zn, cn, idxi, idxO);

    dim3 gD(M_TOT / D_ROWS, F_DIM / 64);
    k_out<<<gD, 256, 0, stream>>>(idxi, cn, wT, out);

    k_loss<<<M_TOT / 4, 256, 0, stream>>>(zn, cn, idxi, lossp);
    k_loss_final<<<1, 256, 0, stream>>>(lossp, lossO);
}

// Round 11
// 195.571 us; speedup vs baseline: 1.0873x; 1.0873x over previous
//
#include <hip/hip_runtime.h>
#include <hip/hip_bf16.h>
#include <math.h>

#define M_TOT   16384      // B*N = 4*4096
#define F_DIM   768
#define C_DIM   64
#define P_DIM   8192
#define EPSN    1e-12f
#define NEG_BIG (-3.402823466e38f)
#define NCH     16
#define PCH     (P_DIM / NCH)   // 512
#define GRP     32
#define NGRP    (P_DIM / GRP)   // 256
#define MARG    1e-2f           // >= 2 * 4e-3 hard bf16x1 screen error bound

typedef __attribute__((ext_vector_type(8))) short bf16x8;
typedef __attribute__((ext_vector_type(4))) float f32x4;
typedef unsigned short ushort_t;
typedef const __attribute__((address_space(1))) void* gas1_t;
typedef __attribute__((address_space(3))) void* las3_t;

__device__ inline ushort_t bf16hi(float v) {
    __hip_bfloat16 hb = __float2bfloat16(v);
    return *reinterpret_cast<ushort_t*>(&hb);
}

// ---------------- Kernel A: cn = l2norm(codebook) + bf16 round ----------------
__global__ void k_norm_cb(const float* __restrict__ cb, float* __restrict__ cn,
                          ushort_t* __restrict__ ch) {
    int wv = threadIdx.x >> 6, lane = threadIdx.x & 63;
    int row = blockIdx.x * 4 + wv;
    float v = cb[(size_t)row * C_DIM + lane];
    float s = v * v;
    #pragma unroll
    for (int o = 32; o; o >>= 1) s += __shfl_xor(s, o, 64);
    float inv = 1.0f / fmaxf(sqrtf(s), EPSN);
    float nv = v * inv;
    size_t i = (size_t)row * C_DIM + lane;
    cn[i] = nv;
    ch[i] = bf16hi(nv);
}

// ---------------- Kernel A2: w_outT[c][f] = w_out[f][c] ----------------
__global__ void k_transpose_wout(const float* __restrict__ w_out, float* __restrict__ wT) {
    int i = blockIdx.x * 256 + threadIdx.x;   // 49152 total
    int f = i >> 6, c = i & 63;
    wT[(size_t)c * F_DIM + f] = w_out[i];
}

// ---------------- Kernel B: zn = l2norm(z @ w_in^T), tiled LDS fp32 GEMM ----------
// Staging via global_load_lds (async DMA, no staging VGPRs -> no spills, no
// ds_writes). LDS dest is linear in lane order (wave-uniform base + lane*16, the
// HW-required form); the XOR swizzle lives in the pre-swizzled GLOBAL source
// address (same involution the reads use). Double-buffered: stage(next) issued
// before compute(cur); __syncthreads() (compiler vmcnt(0)+barrier) drains after
// compute has covered the latency. Compute/FMA chain bitwise-identical to r10.
#define PBM 32
#define PKC 64
__global__ __launch_bounds__(128)
void k_proj(const float* __restrict__ z, const float* __restrict__ w_in,
            float* __restrict__ zn, ushort_t* __restrict__ zh) {
    __shared__ float lz[2][PBM * PKC];     // 2 x 8 KB   [row][slot*4]
    __shared__ float lw[2][C_DIM * PKC];   // 2 x 16 KB  [c][slot*4]

    const int t  = threadIdx.x;
    const int m0 = blockIdx.x * PBM;
    const int r0 = (t >> 4) * 4;        // rows r0..r0+3
    const int c0 = (t & 15) * 4;        // cols c0..c0+3
    const int zswz = t >> 4;            // == ((r0+ri)>>2)&15 for ri<4
    const int wswz = t & 15;            // == ((c0+cj)>>2)&15 for cj<4

    float acc[4][4];
    #pragma unroll
    for (int i = 0; i < 4; ++i)
        #pragma unroll
        for (int j = 0; j < 4; ++j) acc[i][j] = 0.0f;

    // stage chunk 0 into buffer 0
    #pragma unroll
    for (int i = 0; i < 4; ++i) {
        int f4 = i * 128 + t; int row = f4 >> 4, s4 = f4 & 15;
        __builtin_amdgcn_global_load_lds(
            (gas1_t)(z + (size_t)(m0 + row) * F_DIM + (s4 ^ ((row >> 2) & 15)) * 4),
            (las3_t)(&lz[0][f4 * 4]), 16, 0, 0);
    }
    #pragma unroll
    for (int i = 0; i < 8; ++i) {
        int f4 = i * 128 + t; int c = f4 >> 4, s4 = f4 & 15;
        __builtin_amdgcn_global_load_lds(
            (gas1_t)(w_in + (size_t)c * F_DIM + (s4 ^ ((c >> 2) & 15)) * 4),
            (las3_t)(&lw[0][f4 * 4]), 16, 0, 0);
    }
    __syncthreads();

    int cur = 0;
    for (int k0 = 0; k0 < F_DIM; k0 += PKC) {       // 12 chunks
        if (k0 + PKC < F_DIM) {                     // issue next-chunk DMA first
            int nxt = cur ^ 1;
            #pragma unroll
            for (int i = 0; i < 4; ++i) {
                int f4 = i * 128 + t; int row = f4 >> 4, s4 = f4 & 15;
                __builtin_amdgcn_global_load_lds(
                    (gas1_t)(z + (size_t)(m0 + row) * F_DIM + k0 + PKC
                             + (s4 ^ ((row >> 2) & 15)) * 4),
                    (las3_t)(&lz[nxt][f4 * 4]), 16, 0, 0);
            }
            #pragma unroll
            for (int i = 0; i < 8; ++i) {
                int f4 = i * 128 + t; int c = f4 >> 4, s4 = f4 & 15;
                __builtin_amdgcn_global_load_lds(
                    (gas1_t)(w_in + (size_t)c * F_DIM + k0 + PKC
                             + (s4 ^ ((c >> 2) & 15)) * 4),
                    (las3_t)(&lw[nxt][f4 * 4]), 16, 0, 0);
            }
        }

        const float* lzb = lz[cur];
        const float* lwb = lw[cur];
        #pragma unroll
        for (int kq = 0; kq < 16; ++kq) {
            float4 zf[4], wf[4];
            int zo = (kq ^ zswz) * 4;
            int wo = (kq ^ wswz) * 4;
            #pragma unroll
            for (int ri = 0; ri < 4; ++ri)
                zf[ri] = *(const float4*)(lzb + (r0 + ri) * PKC + zo);
            #pragma unroll
            for (int cj = 0; cj < 4; ++cj)
                wf[cj] = *(const float4*)(lwb + (c0 + cj) * PKC + wo);
            #pragma unroll
            for (int ri = 0; ri < 4; ++ri)
                #pragma unroll
                for (int cj = 0; cj < 4; ++cj) {
                    acc[ri][cj] = fmaf(zf[ri].x, wf[cj].x, acc[ri][cj]);
                    acc[ri][cj] = fmaf(zf[ri].y, wf[cj].y, acc[ri][cj]);
                    acc[ri][cj] = fmaf(zf[ri].z, wf[cj].z, acc[ri][cj]);
                    acc[ri][cj] = fmaf(zf[ri].w, wf[cj].w, acc[ri][cj]);
                }
        }
        __syncthreads();    // vmcnt(0)+barrier: next chunk landed, cur free
        cur ^= 1;
    }

    // ---- epilogue: row-norm (16-lane group holds one row's 64 c) ----
    #pragma unroll
    for (int ri = 0; ri < 4; ++ri) {
        float s = acc[ri][0] * acc[ri][0] + acc[ri][1] * acc[ri][1]
                + acc[ri][2] * acc[ri][2] + acc[ri][3] * acc[ri][3];
        #pragma unroll
        for (int o = 1; o < 16; o <<= 1) s += __shfl_xor(s, o, 64);
        float inv = 1.0f / fmaxf(sqrtf(s), EPSN);
        float4 v;
        v.x = acc[ri][0] * inv; v.y = acc[ri][1] * inv;
        v.z = acc[ri][2] * inv; v.w = acc[ri][3] * inv;
        size_t base = (size_t)(m0 + r0 + ri) * C_DIM + c0;
        *(float4*)(zn + base) = v;
        ushort4 hv = {bf16hi(v.x), bf16hi(v.y), bf16hi(v.z), bf16hi(v.w)};
        *(ushort4*)(zh + base) = hv;
    }
}

// ---------------- Kernel C: bf16x1 MFMA screen -> per-32-code group maxima ----------
// Single-precision screen: sim_bf16 = zh . ch, |err| <= 4e-3 hard (C-S bound on
// unit rows); k_pick rescans in exact fp32 with MARG = 1e-2 >= 2*err. 2 MFMAs per
// 16(p)x16(m)xK64 tile. gmax[NGRP][M_TOT] hosted in d_out 'out' region.
__global__ __launch_bounds__(256, 4)
void k_simmax(const ushort_t* __restrict__ zh, const ushort_t* __restrict__ ch,
              float* __restrict__ gmax) {
    int wv = threadIdx.x >> 6, l = threadIdx.x & 63;
    int m0 = (blockIdx.x * 4 + wv) * 64;
    int p0 = blockIdx.y * PCH;
    int col = l & 15, quad = l >> 4;
    int kb = quad * 8;

    bf16x8 bh[4][2];
    #pragma unroll
    for (int mt = 0; mt < 4; ++mt) {
        const ushort_t* zr = zh + (size_t)(m0 + mt * 16 + col) * C_DIM + kb;
        #pragma unroll
        for (int ks = 0; ks < 2; ++ks)
            bh[mt][ks] = *(const bf16x8*)(zr + ks * 32);
    }

    for (int g = 0; g < PCH / GRP; ++g) {           // 16 groups of 32 p
        float gm[4];
        #pragma unroll
        for (int mt = 0; mt < 4; ++mt) gm[mt] = NEG_BIG;

        #pragma unroll
        for (int half = 0; half < 2; ++half) {      // 2 16-p tiles per group
            int pt = g * 2 + half;
            size_t prow = (size_t)(p0 + pt * 16 + col) * C_DIM + kb;
            bf16x8 ah0 = *(const bf16x8*)(ch + prow);
            bf16x8 ah1 = *(const bf16x8*)(ch + prow + 32);
            #pragma unroll
            for (int mt = 0; mt < 4; ++mt) {
                f32x4 acc = {0.f, 0.f, 0.f, 0.f};
                acc = __builtin_amdgcn_mfma_f32_16x16x32_bf16(ah0, bh[mt][0], acc, 0, 0, 0);
                acc = __builtin_amdgcn_mfma_f32_16x16x32_bf16(ah1, bh[mt][1], acc, 0, 0, 0);
                float tm = fmaxf(fmaxf(acc[0], acc[1]), fmaxf(acc[2], acc[3]));
                gm[mt] = fmaxf(gm[mt], tm);
            }
        }
        #pragma unroll
        for (int mt = 0; mt < 4; ++mt) {
            float v = gm[mt];
            v = fmaxf(v, __shfl_xor(v, 16, 64));
            v = fmaxf(v, __shfl_xor(v, 32, 64));
            if (quad == 0)
                gmax[(size_t)(blockIdx.y * (PCH / GRP) + g) * M_TOT + m0 + mt * 16 + col] = v;
        }
    }
}

// ---------------- Kernel C2: per-row pick, one WAVE per row, wave-parallel rescan ----
// Lane l holds groups {l, l+64, l+128, l+192}. Row max via shuffle; __ballot flags
// candidate groups; for each flagged group (wave-uniform bit loop, ~1.6/row) all 64
// lanes rescan: lane l does half the dot of code g*32+(l&31) (halves via shfl 32).
// Exact fp32, np tie rules (groups ascending, min p on ties). No LDS, no atomics.
__global__ __launch_bounds__(256)
void k_pick(const float* __restrict__ gmax, const float* __restrict__ zn,
            const float* __restrict__ cn, int* __restrict__ idx_i,
            float* __restrict__ idx_f) {
    int wv = threadIdx.x >> 6, l = threadIdx.x & 63;
    int m = blockIdx.x * 4 + wv;            // one wave per row

    float gv[4];
    #pragma unroll
    for (int b = 0; b < 4; ++b)
        gv[b] = gmax[(size_t)(b * 64 + l) * M_TOT + m];
    float rm = fmaxf(fmaxf(gv[0], gv[1]), fmaxf(gv[2], gv[3]));
    #pragma unroll
    for (int o = 32; o; o >>= 1) rm = fmaxf(rm, __shfl_xor(rm, o, 64));
    float thr = rm - MARG;

    // zn row: lane holds half the row (half = l>>5)
    float zr[32];
    {
        const float4* zp = (const float4*)(zn + (size_t)m * C_DIM + (l >> 5) * 32);
        #pragma unroll
        for (int q = 0; q < 8; ++q) {
            float4 v = zp[q];
            zr[4 * q] = v.x; zr[4 * q + 1] = v.y;
            zr[4 * q + 2] = v.z; zr[4 * q + 3] = v.w;
        }
    }

    float bv = NEG_BIG; int bp = P_DIM;
    #pragma unroll
    for (int b = 0; b < 4; ++b) {           // ascending batches -> ascending groups
        unsigned long long mask = __ballot(gv[b] >= thr);
        while (mask) {
            int j = __ffsll((unsigned long long)mask) - 1;
            mask &= mask - 1;               // ascending j within batch
            int g = b * 64 + j;
            int p = g * GRP + (l & 31);
            const float4* cp = (const float4*)(cn + (size_t)p * C_DIM + (l >> 5) * 32);
            float a0 = 0.f, a1 = 0.f, a2 = 0.f, a3 = 0.f;
            #pragma unroll
            for (int q = 0; q < 8; ++q) {
                float4 w = cp[q];
                a0 = fmaf(w.x, zr[4 * q + 0], a0);
                a1 = fmaf(w.y, zr[4 * q + 1], a1);
                a2 = fmaf(w.z, zr[4 * q + 2], a2);
                a3 = fmaf(w.w, zr[4 * q + 3], a3);
            }
            float s = (a0 + a1) + (a2 + a3);
            s += __shfl_xor(s, 32, 64);     // combine halves: full dot in both lanes
            if (s > bv || (s == bv && p < bp)) { bv = s; bp = p; }
        }
    }
    #pragma unroll
    for (int o = 32; o; o >>= 1) {
        float ov = __shfl_xor(bv, o, 64);
        int   op = __shfl_xor(bp, o, 64);
        if (ov > bv || (ov == bv && op < bp)) { bv = ov; bp = op; }
    }
    if (l == 0) { idx_i[m] = bp; idx_f[m] = (float)bp; }
}

// ---------------- Kernel D: out = codes @ w_outT ----------------
#define D_ROWS 128
__global__ void k_out(const int* __restrict__ idx, const float* __restrict__ cn,
                      const float* __restrict__ wT, float* __restrict__ out) {
    int wv = threadIdx.x >> 6, lane = threadIdx.x & 63;
    int f  = blockIdx.y * 64 + lane;
    int m0 = blockIdx.x * D_ROWS + wv * 32;

    float wcol[64];
    #pragma unroll
    for (int c = 0; c < 64; ++c) wcol[c] = wT[(size_t)c * F_DIM + f];

    #pragma unroll 4
    for (int r = 0; r < 32; ++r) {
        int m = __builtin_amdgcn_readfirstlane(m0 + r);
        const float4* cp = (const float4*)(cn + (size_t)idx[m] * C_DIM);
        float acc = 0.f;
        #pragma unroll
        for (int j = 0; j < 16; ++j) {
            float4 cv = cp[j];
            acc = fmaf(cv.x, wcol[4 * j + 0], acc);
            acc = fmaf(cv.y, wcol[4 * j + 1], acc);
            acc = fmaf(cv.z, wcol[4 * j + 2], acc);
            acc = fmaf(cv.w, wcol[4 * j + 3], acc);
        }
        out[(size_t)m * F_DIM + f] = acc;
    }
}

// ---------------- Kernel E: per-block loss partials ----------------
__global__ void k_loss(const float* __restrict__ zn, const float* __restrict__ cn,
                       const int* __restrict__ idx, float* __restrict__ lossp) {
    __shared__ float wsum[4];
    int wv = threadIdx.x >> 6, lane = threadIdx.x & 63;
    int m = blockIdx.x * 4 + wv;
    int ci = idx[m];
    float zv = zn[(size_t)m * C_DIM + lane];
    float cv = cn[(size_t)ci * C_DIM + lane];
    float d = zv - cv;
    float s = d * d;
    #pragma unroll
    for (int o = 32; o; o >>= 1) s += __shfl_xor(s, o, 64);
    if (lane == 0) wsum[wv] = s;
    __syncthreads();
    if (threadIdx.x == 0) lossp[blockIdx.x] = (wsum[0] + wsum[1]) + (wsum[2] + wsum[3]);
}

__global__ void k_loss_final(const float* __restrict__ lossp, float* __restrict__ loss_out) {
    __shared__ float sh[256];
    float s = 0.f;
    for (int i = threadIdx.x; i < 4096; i += 256) s += lossp[i];
    sh[threadIdx.x] = s;
    __syncthreads();
    for (int o = 128; o; o >>= 1) {
        if (threadIdx.x < o) sh[threadIdx.x] += sh[threadIdx.x + o];
        __syncthreads();
    }
    if (threadIdx.x == 0)
        loss_out[0] = 1.25f * sh[0] / (float)(M_TOT * C_DIM);
}

extern "C" void kernel_launch(void* const* d_in, const int* in_sizes, int n_in,
                              void* d_out, int out_size, void* d_ws, size_t ws_size,
                              hipStream_t stream) {
    const float* z     = (const float*)d_in[0];
    const float* w_in  = (const float*)d_in[1];
    const float* w_out = (const float*)d_in[2];
    const float* cb    = (const float*)d_in[3];

    float* out    = (float*)d_out;
    float* lossO  = out + (size_t)M_TOT * F_DIM;
    float* idxO   = lossO + 1;
    // gmax (16.8 MB) lives in the d_out 'out' region: written by k_simmax, read
    // by k_pick, then fully overwritten by k_out afterwards (stream-ordered).
    float* gmax   = out;

    float* ws    = (float*)d_ws;                          // total ~9.4 MB
    float* cn    = ws;                                    // 524288 f   (2 MB)
    float* zn    = cn + (size_t)P_DIM * C_DIM;            // 1048576 f  (4 MB)
    float* wT    = zn + (size_t)M_TOT * C_DIM;            // 49152 f
    float* lossp = wT + (size_t)C_DIM * F_DIM;            // 4096 f
    int*   idxi  = (int*)(lossp + 4096);                  // 16384 i
    ushort_t* zh = (ushort_t*)(idxi + M_TOT);             // 1048576 us (2 MB)
    ushort_t* ch = zh + (size_t)M_TOT * C_DIM;            // 524288 us  (1 MB)

    k_norm_cb<<<P_DIM / 4, 256, 0, stream>>>(cb, cn, ch);
    k_transpose_wout<<<(C_DIM * F_DIM) / 256, 256, 0, stream>>>(w_out, wT);
    k_proj<<<M_TOT / PBM, 128, 0, stream>>>(z, w_in, zn, zh);

    dim3 gC(M_TOT / 256, NCH);
    k_simmax<<<gC, 256, 0, stream>>>(zh, ch, gmax);
    k_pick<<<M_TOT / 4, 256, 0, stream>>>(gmax, zn, cn, idxi, idxO);

    dim3 gD(M_TOT / D_ROWS, F_DIM / 64);
    k_out<<<gD, 256, 0, stream>>>(idxi, cn, wT, out);

    k_loss<<<M_TOT / 4, 256, 0, stream>>>(zn, cn, idxi, lossp);
    k_loss_final<<<1, 256, 0, stream>>>(lossp, lossO);
}